// Round 6
// baseline (479.180 us; speedup 1.0000x reference)
//
#include <hip/hip_runtime.h>
#include <hip/hip_bf16.h>

#define B_    32
#define N_    6
#define D_    41
#define C_    64
#define FH_   4
#define FW_   6
#define INCH  768
#define HW    24
#define O_    105
#define PBN   984
#define PPB   5904
#define NPTS  188928
#define FINAL_ELEMS 81920000
#define NSEG  8          // planes per b (5000 voxels each)
#define SEGV  5000       // voxels per segment
#define CONVB 768        // 192 bn x 4 hw-quarters; geom blocks follow
#define XSL   772        // xs column stride (772%32==4 -> bank-staggered cols)

// ws: feat f32[192*1536] | depth f32[NPTS] | cnt i32[256] | entries u32[256*PPB]
// entry = { d(6b)<<21 | nhw(8b)<<13 | rel(13b) }

// ---------------------------------------------------------------------------
// K1 fused dispatch: blocks [0,768) = conv+softmax, each (bn, hw-quarter):
// all 105 rows x 6 hw cols (softmax over D is per-hw -> block-local).
// blocks [768,1506) = geometry+compaction (bit-identical binning arithmetic).
// 21KB LDS -> ~6 blocks/CU co-resident: conv latency hidden by TLP, geom
// runs fully in parallel. Conv accumulation order per output unchanged ->
// bit-identical results.
// ---------------------------------------------------------------------------
__global__ __launch_bounds__(256) void k_fused(
    const float* __restrict__ x, const float* __restrict__ w,
    const float* __restrict__ bias,
    const float* __restrict__ m1, const float* __restrict__ trans,
    const float* __restrict__ m2,
    float* __restrict__ feat_ws, float* __restrict__ depth_ws,
    float* __restrict__ dlogit,
    int* __restrict__ cnt, unsigned* __restrict__ entries)
{
    __shared__ float xs[6 * XSL];   // x cols [q*6,q*6+6), col-major, 18.1 KB
    __shared__ float ys[O_ * 6];    // y[105][6] for this quarter (2.5 KB)
    __shared__ float smax[6], srs[6];

    const int t = threadIdx.x;

    if (blockIdx.x < CONVB) {
        // =================== CONV PATH ===================
        const int bn = blockIdx.x >> 2;
        const int q  = blockIdx.x & 3;        // hw quarter: cols q*6..q*6+5
        const int og  = t / 6;                // 35 groups x 3 rows
        const int col = t % 6;                // local col 0..5

        // stage: x[bn][c][q*6+j] -> xs[col][c] (transposed, stride XSL)
        const float2* xg2 = (const float2*)(x + (size_t)bn * (INCH * HW));
        for (int i = t; i < 2304; i += 256) {   // 768 ch x 3 float2
            int c = i / 3, j = i - c * 3;
            float2 v = xg2[c * 12 + q * 3 + j];
            xs[(2 * j + 0) * XSL + c] = v.x;
            xs[(2 * j + 1) * XSL + c] = v.y;
        }
        __syncthreads();

        if (t < 210) {
            const int o0 = og * 3;
            const float4* wr0 = (const float4*)(w + (size_t)(o0 + 0) * INCH);
            const float4* wr1 = (const float4*)(w + (size_t)(o0 + 1) * INCH);
            const float4* wr2 = (const float4*)(w + (size_t)(o0 + 2) * INCH);
            const float* xcol = xs + col * XSL;
            float a0 = 0.f, a1 = 0.f, a2 = 0.f;
            for (int c4 = 0; c4 < 192; ++c4) {
                float4 w0 = wr0[c4];
                float4 w1 = wr1[c4];
                float4 w2 = wr2[c4];
                float4 xv = *(const float4*)(xcol + c4 * 4);  // 1 ds_read_b128
                a0 = fmaf(w0.x, xv.x, a0); a0 = fmaf(w0.y, xv.y, a0);
                a0 = fmaf(w0.z, xv.z, a0); a0 = fmaf(w0.w, xv.w, a0);
                a1 = fmaf(w1.x, xv.x, a1); a1 = fmaf(w1.y, xv.y, a1);
                a1 = fmaf(w1.z, xv.z, a1); a1 = fmaf(w1.w, xv.w, a1);
                a2 = fmaf(w2.x, xv.x, a2); a2 = fmaf(w2.y, xv.y, a2);
                a2 = fmaf(w2.z, xv.z, a2); a2 = fmaf(w2.w, xv.w, a2);
            }
            ys[(o0 + 0) * 6 + col] = a0 + bias[o0 + 0];
            ys[(o0 + 1) * 6 + col] = a1 + bias[o0 + 1];
            ys[(o0 + 2) * 6 + col] = a2 + bias[o0 + 2];
        }
        __syncthreads();

        if (t < 6) {
            float mx = -1e30f;
            for (int d = 0; d < D_; d++) mx = fmaxf(mx, ys[d * 6 + t]);
            float s = 0.f;
            for (int d = 0; d < D_; d++) s = __fadd_rn(s, expf(__fsub_rn(ys[d * 6 + t], mx)));
            smax[t] = mx; srs[t] = s;
        }
        __syncthreads();

        for (int u = t; u < D_ * 6; u += 256) {
            int d = u / 6, col2 = u - d * 6;
            float yv = ys[u];
            int gidx = bn * PBN + d * HW + q * 6 + col2;
            depth_ws[gidx] = __fdiv_rn(expf(__fsub_rn(yv, smax[col2])), srs[col2]);
            dlogit[(size_t)gidx] = yv;
        }
        for (int u = t; u < C_ * 6; u += 256) {
            int c = u / 6, col2 = u - c * 6;
            feat_ws[(size_t)bn * (C_ * HW) + c * HW + q * 6 + col2] = ys[(D_ + c) * 6 + col2];
        }
        return;
    }

    // =================== GEOM PATH ===================
    __shared__ int lcnt[16], lbase[16];

    const float* rots = (fabsf(m1[0]) > 50.0f) ? m2 : m1;
    const float* intr = (fabsf(m1[0]) > 50.0f) ? m1 : m2;

    const int gb0 = blockIdx.x - CONVB;       // 0..737
    int p = gb0 * 256 + t;                    // 738*256 == 188928
    if (t < 16) lcnt[t] = 0;
    __syncthreads();

    int b  = p / PPB;
    int pl = p % PPB;
    int n  = pl / PBN;
    int r  = pl % PBN;
    int d  = r / HW;
    int hw = r % HW;
    int h = hw / FW_, wp = hw % FW_;

    float dv = 4.0f + (float)d;
    float xi = (float)((double)wp * (199.0 / 5.0));
    float yi = (float)((double)h  * (149.0 / 3.0));
    float px = __fmul_rn(xi, dv), py = __fmul_rn(yi, dv), pz = dv;

    int bn = b * N_ + n;
    const float* K = intr + bn * 9;
    const float* R = rots + bn * 9;
    const float* T = trans + bn * 3;

    float a00 = K[0], a01 = K[1], a02 = K[2];
    float a11 = K[4], a12 = K[5];
    float a22 = K[8];

    float i00 = __fdiv_rn(1.0f, a00);
    float i11 = __fdiv_rn(1.0f, a11);
    float x0  = __fmul_rn(a01, i00);
    float i01 = __fmul_rn(-i11, x0);
    float i22 = __fdiv_rn(1.0f, a22);
    float y0  = __fmul_rn(a02, i00);
    y0 = __fadd_rn(y0, __fmul_rn(a12, i01));
    float y1  = __fmul_rn(a12, i11);
    float i02 = __fmul_rn(-i22, y0);
    float i12 = __fmul_rn(-i22, y1);
    float i10 = 0.f, i20 = 0.f, i21 = 0.f;

    float r00 = R[0], r01 = R[1], r02 = R[2];
    float r10 = R[3], r11 = R[4], r12 = R[5];
    float r20 = R[6], r21 = R[7], r22 = R[8];

#define MM(u0,u1,u2, v0,v1,v2) \
    __fmaf_rn(u2, v2, __fmaf_rn(u1, v1, __fmul_rn(u0, v0)))
    float c00 = MM(r00, r01, r02, i00, i10, i20);
    float c01 = MM(r00, r01, r02, i01, i11, i21);
    float c02 = MM(r00, r01, r02, i02, i12, i22);
    float c10 = MM(r10, r11, r12, i00, i10, i20);
    float c11 = MM(r10, r11, r12, i01, i11, i21);
    float c12 = MM(r10, r11, r12, i02, i12, i22);
    float c20 = MM(r20, r21, r22, i00, i10, i20);
    float c21 = MM(r20, r21, r22, i01, i11, i21);
    float c22 = MM(r20, r21, r22, i02, i12, i22);
#undef MM

#define DOT3(u0,v0,u1,v1,u2,v2) \
    __fadd_rn(__fadd_rn(__fmul_rn(u0,v0), __fmul_rn(u1,v1)), __fmul_rn(u2,v2))
    float gx = __fadd_rn(DOT3(c00,px, c01,py, c02,pz), T[0]);
    float gy = __fadd_rn(DOT3(c10,px, c11,py, c12,pz), T[1]);
    float gz = __fadd_rn(DOT3(c20,px, c21,py, c22,pz), T[2]);
#undef DOT3

    int ix = (int)__fmul_rn(__fadd_rn(gx, 50.0f), 2.0f);
    int iy = (int)__fmul_rn(__fadd_rn(gy, 50.0f), 2.0f);
    int iz = (int)__fdiv_rn(__fadd_rn(gz, 10.0f), 20.0f);
    bool kept = (ix >= 0) && (ix < 200) && (iy >= 0) && (iy < 200) && (iz == 0);

    const int bmin = (gb0 * 256) / PPB;       // block spans b in {bmin, bmin+1}
    int lb = 0, slot = 0;
    unsigned epack = 0;
    if (kept) {
        int vl  = ix * 200 + iy;          // 0..39999
        int g   = vl / SEGV;              // segment 0..7
        int rel = vl - g * SEGV;          // 0..4999  (13 bits)
        int nhw = n * HW + hw;            // 0..143   (8 bits)
        epack = (unsigned)rel | ((unsigned)nhw << 13) | ((unsigned)d << 21);
        lb  = (b - bmin) * NSEG + g;      // 0..15
        slot = atomicAdd(&lcnt[lb], 1);   // LDS atomic: fast
    }
    __syncthreads();
    if (t < 16 && lcnt[t] > 0) {
        int gbk = (bmin + (t >> 3)) * NSEG + (t & 7);
        lbase[t] = atomicAdd(&cnt[gbk], lcnt[t]);
    }
    __syncthreads();
    if (kept) {
        int gbk = (bmin + (lb >> 3)) * NSEG + (lb & 7);
        entries[(size_t)gbk * PPB + lbase[lb] + slot] = epack;
    }
}

// ---------------------------------------------------------------------------
// K3: splat -> f32 out (unchanged from R5). One block per (b,c,segment);
// 20KB LDS plane; compacted 4B-entry scan (depth re-gathered from
// L2-resident depth_ws); LDS atomics; coalesced float4 stores.
// ---------------------------------------------------------------------------
__global__ __launch_bounds__(256) void k_splat(
    const float* __restrict__ feat, const float* __restrict__ depth,
    const int* __restrict__ cnt, const unsigned* __restrict__ entries,
    float* __restrict__ out)
{
    __shared__ float plane[SEGV];         // 20 KB
    __shared__ float ftab[144];           // feat[b, n, c, hw] for this c
    int bid = blockIdx.x;
    int b   = bid >> 9;                   // /512
    int rem = bid & 511;
    int c   = rem >> 3;
    int g   = rem & 7;
    int t   = threadIdx.x;
    float4* pl4 = (float4*)plane;

    for (int i = t; i < SEGV / 4; i += 256) pl4[i] = make_float4(0.f, 0.f, 0.f, 0.f);
    if (t < 144) {
        int n  = t / HW;
        int hw = t - n * HW;
        ftab[t] = feat[(size_t)(b * N_ + n) * (C_ * HW) + c * HW + hw];
    }
    __syncthreads();

    const int bkt = b * NSEG + g;
    const int ne = cnt[bkt];
    const unsigned* eb = entries + (size_t)bkt * PPB;
    const float* db = depth + (size_t)b * PPB;
    for (int i = t; i < ne; i += 256) {
        unsigned e = eb[i];
        int rel = e & 8191u;
        int nhw = (e >> 13) & 255u;
        int d   = e >> 21;
        int n   = nhw / HW;
        int hw  = nhw - n * HW;
        float dp = db[n * PBN + d * HW + hw];
        atomicAdd(&plane[rel], dp * ftab[nhw]);
    }
    __syncthreads();

    float4* ob = (float4*)(out + ((size_t)(b * C_ + c) * 40000) + g * SEGV);
    for (int i = t; i < SEGV / 4; i += 256) ob[i] = pl4[i];
}

// ---------------------------------------------------------------------------
extern "C" void kernel_launch(void* const* d_in, const int* in_sizes, int n_in,
                              void* d_out, int out_size, void* d_ws, size_t ws_size,
                              hipStream_t stream) {
    const float *x = nullptr, *m1 = nullptr, *m2 = nullptr, *trn = nullptr,
                *w = nullptr, *bias = nullptr;
    for (int i = 0; i < n_in; i++) {
        const float* p = (const float*)d_in[i];
        switch (in_sizes[i]) {
            case 3538944: x = p; break;
            case 1728:    if (!m1) m1 = p; else m2 = p; break;
            case 576:     trn = p; break;
            case 80640:   w = p; break;
            case 105:     bias = p; break;
            default: break;
        }
    }
    if (!x)    x    = (const float*)d_in[0];
    if (!m1)   m1   = (const float*)d_in[1];
    if (!trn)  trn  = (const float*)d_in[2];
    if (!m2)   m2   = (const float*)d_in[3];
    if (!w)    w    = (const float*)d_in[4];
    if (!bias) bias = (const float*)d_in[5];

    float*    feat_ws  = (float*)d_ws;                 // 192*1536 f32
    float*    depth_ws = feat_ws + 192 * C_ * HW;      // NPTS f32
    int*      cnt      = (int*)(depth_ws + NPTS);      // 256 i32
    unsigned* entries  = (unsigned*)(cnt + 256);       // 256*PPB u32 (~6 MB)

    float* out    = (float*)d_out;
    float* dlogit = out + FINAL_ELEMS;

    hipMemsetAsync(cnt, 0, 256 * sizeof(int), stream);
    k_fused<<<CONVB + 738, 256, 0, stream>>>(x, w, bias, m1, trn, m2,
                                             feat_ws, depth_ws, dlogit,
                                             cnt, entries);
    k_splat<<<16384, 256, 0, stream>>>(feat_ws, depth_ws, cnt, entries, out);
}

// Round 7
// 469.423 us; speedup vs baseline: 1.0208x; 1.0208x over previous
//
#include <hip/hip_runtime.h>
#include <hip/hip_bf16.h>

#define B_    32
#define N_    6
#define D_    41
#define C_    64
#define FH_   4
#define FW_   6
#define INCH  768
#define HW    24
#define O_    105
#define PBN   984
#define PPB   5904
#define NPTS  188928
#define FINAL_ELEMS 81920000
#define CONVB 192        // conv blocks (R5 form); geom blocks follow
#define CH    240        // voxels per chunk (plane rows)
#define NCH   167        // chunks per b: 166*240 + 160 = 40000
#define NBKT  (B_ * NCH) // 5344 buckets
#define ESTR  2048       // entry slots per bucket (avg ~9, huge margin)
#define PLS   65         // plane c-stride (odd -> 2-way banks on atomics)

// ws: feat f32[192*1536] ([bn][hw][c] layout!) | depth f32[NPTS] |
//     cnt i32[NBKT] | entries u32[NBKT*ESTR]
// entry = { d(6b)<<16 | hw(5b)<<11 | n(3b)<<8 | rel(8b) }

// ---------------------------------------------------------------------------
// K1 fused dispatch: blocks [0,192) = conv+softmax (R2/R5 form, 34us known);
// blocks [192,930) = geometry + chunk-bucketed compaction (binning arithmetic
// bit-identical to the validated frozen version; only pack/bucket changed).
// ---------------------------------------------------------------------------
__global__ __launch_bounds__(256) void k_fused(
    const float* __restrict__ x, const float* __restrict__ w,
    const float* __restrict__ bias,
    const float* __restrict__ m1, const float* __restrict__ trans,
    const float* __restrict__ m2,
    float* __restrict__ feat_ws, float* __restrict__ depth_ws,
    float* __restrict__ dlogit,
    int* __restrict__ cnt, unsigned* __restrict__ entries)
{
    __shared__ float xs[9216];      // half of x[bn]: 384 c x 24 hw (36 KB)
    __shared__ float ys[O_ * HW];   // full y image (10 KB)
    __shared__ float smax[HW], srs[HW];
    __shared__ int lcnt[2 * NCH], lbase[2 * NCH];   // geom path (2.7 KB)

    const int t = threadIdx.x;

    if (blockIdx.x < CONVB) {
        // =================== CONV PATH (R5 form) ===================
        const int bn = blockIdx.x;
        const int og = t / 6;           // 35 groups x 3 rows = 105
        const int q6 = t % 6;           // hw quad

        float a[3][4] = {{0.f,0.f,0.f,0.f},{0.f,0.f,0.f,0.f},{0.f,0.f,0.f,0.f}};
        const int o0 = og * 3;
        const float4* wr0 = (const float4*)(w + (size_t)(o0 + 0) * INCH);
        const float4* wr1 = (const float4*)(w + (size_t)(o0 + 1) * INCH);
        const float4* wr2 = (const float4*)(w + (size_t)(o0 + 2) * INCH);
        float4* xs4 = (float4*)xs;

        for (int half = 0; half < 2; ++half) {
            if (half) __syncthreads();                 // drain half-0 readers
            const float4* xg = (const float4*)(x + (size_t)bn * (INCH * HW)) + half * 2304;
            for (int i = t; i < 2304; i += 256) xs4[i] = xg[i];
            __syncthreads();

            if (t < 210) {
                const int wb = half * 96;              // float4 index into w row
                for (int c4 = 0; c4 < 96; ++c4) {
                    float4 w0 = wr0[wb + c4];
                    float4 w1 = wr1[wb + c4];
                    float4 w2 = wr2[wb + c4];
                    int cb = c4 * 4;
                    float4 x0 = xs4[(cb + 0) * 6 + q6];
                    float4 x1 = xs4[(cb + 1) * 6 + q6];
                    float4 x2 = xs4[(cb + 2) * 6 + q6];
                    float4 x3 = xs4[(cb + 3) * 6 + q6];
                    a[0][0]=fmaf(w0.x,x0.x,a[0][0]); a[0][1]=fmaf(w0.x,x0.y,a[0][1]);
                    a[0][2]=fmaf(w0.x,x0.z,a[0][2]); a[0][3]=fmaf(w0.x,x0.w,a[0][3]);
                    a[1][0]=fmaf(w1.x,x0.x,a[1][0]); a[1][1]=fmaf(w1.x,x0.y,a[1][1]);
                    a[1][2]=fmaf(w1.x,x0.z,a[1][2]); a[1][3]=fmaf(w1.x,x0.w,a[1][3]);
                    a[2][0]=fmaf(w2.x,x0.x,a[2][0]); a[2][1]=fmaf(w2.x,x0.y,a[2][1]);
                    a[2][2]=fmaf(w2.x,x0.z,a[2][2]); a[2][3]=fmaf(w2.x,x0.w,a[2][3]);
                    a[0][0]=fmaf(w0.y,x1.x,a[0][0]); a[0][1]=fmaf(w0.y,x1.y,a[0][1]);
                    a[0][2]=fmaf(w0.y,x1.z,a[0][2]); a[0][3]=fmaf(w0.y,x1.w,a[0][3]);
                    a[1][0]=fmaf(w1.y,x1.x,a[1][0]); a[1][1]=fmaf(w1.y,x1.y,a[1][1]);
                    a[1][2]=fmaf(w1.y,x1.z,a[1][2]); a[1][3]=fmaf(w1.y,x1.w,a[1][3]);
                    a[2][0]=fmaf(w2.y,x1.x,a[2][0]); a[2][1]=fmaf(w2.y,x1.y,a[2][1]);
                    a[2][2]=fmaf(w2.y,x1.z,a[2][2]); a[2][3]=fmaf(w2.y,x1.w,a[2][3]);
                    a[0][0]=fmaf(w0.z,x2.x,a[0][0]); a[0][1]=fmaf(w0.z,x2.y,a[0][1]);
                    a[0][2]=fmaf(w0.z,x2.z,a[0][2]); a[0][3]=fmaf(w0.z,x2.w,a[0][3]);
                    a[1][0]=fmaf(w1.z,x2.x,a[1][0]); a[1][1]=fmaf(w1.z,x2.y,a[1][1]);
                    a[1][2]=fmaf(w1.z,x2.z,a[1][2]); a[1][3]=fmaf(w1.z,x2.w,a[1][3]);
                    a[2][0]=fmaf(w2.z,x2.x,a[2][0]); a[2][1]=fmaf(w2.z,x2.y,a[2][1]);
                    a[2][2]=fmaf(w2.z,x2.z,a[2][2]); a[2][3]=fmaf(w2.z,x2.w,a[2][3]);
                    a[0][0]=fmaf(w0.w,x3.x,a[0][0]); a[0][1]=fmaf(w0.w,x3.y,a[0][1]);
                    a[0][2]=fmaf(w0.w,x3.z,a[0][2]); a[0][3]=fmaf(w0.w,x3.w,a[0][3]);
                    a[1][0]=fmaf(w1.w,x3.x,a[1][0]); a[1][1]=fmaf(w1.w,x3.y,a[1][1]);
                    a[1][2]=fmaf(w1.w,x3.z,a[1][2]); a[1][3]=fmaf(w1.w,x3.w,a[1][3]);
                    a[2][0]=fmaf(w2.w,x3.x,a[2][0]); a[2][1]=fmaf(w2.w,x3.y,a[2][1]);
                    a[2][2]=fmaf(w2.w,x3.z,a[2][2]); a[2][3]=fmaf(w2.w,x3.w,a[2][3]);
                }
            }
        }

        if (t < 210) {
#pragma unroll
            for (int r = 0; r < 3; r++) {
                float bo = bias[o0 + r];
#pragma unroll
                for (int j = 0; j < 4; j++)
                    ys[(o0 + r) * HW + q6 * 4 + j] = a[r][j] + bo;
            }
        }
        __syncthreads();

        if (t < HW) {
            float mx = -1e30f;
            for (int d = 0; d < D_; d++) mx = fmaxf(mx, ys[d * HW + t]);
            float s = 0.f;
            for (int d = 0; d < D_; d++) s = __fadd_rn(s, expf(__fsub_rn(ys[d * HW + t], mx)));
            smax[t] = mx; srs[t] = s;
        }
        __syncthreads();

        for (int u = t; u < D_ * HW; u += 256) {
            float yv = ys[u];
            int hw = u % HW;
            depth_ws[bn * PBN + u] = __fdiv_rn(expf(__fsub_rn(yv, smax[hw])), srs[hw]);
            dlogit[(size_t)bn * PBN + u] = yv;
        }
        // feat epilogue: NEW layout [bn][hw][c] so splat reads c-contiguous rows
        for (int u = t; u < C_ * HW; u += 256) {
            int hw = u >> 6;            // u = hw*64 + c
            int c  = u & 63;
            feat_ws[(size_t)(bn * HW + hw) * C_ + c] = ys[(D_ + c) * HW + hw];
        }
        return;
    }

    // =================== GEOM PATH ===================
    const float* rots = (fabsf(m1[0]) > 50.0f) ? m2 : m1;
    const float* intr = (fabsf(m1[0]) > 50.0f) ? m1 : m2;

    const int gb0 = blockIdx.x - CONVB;       // 0..737
    int p = gb0 * 256 + t;                    // 738*256 == 188928
    for (int i = t; i < 2 * NCH; i += 256) lcnt[i] = 0;
    __syncthreads();

    int b  = p / PPB;
    int pl = p % PPB;
    int n  = pl / PBN;
    int r  = pl % PBN;
    int d  = r / HW;
    int hw = r % HW;
    int h = hw / FW_, wp = hw % FW_;

    float dv = 4.0f + (float)d;
    float xi = (float)((double)wp * (199.0 / 5.0));
    float yi = (float)((double)h  * (149.0 / 3.0));
    float px = __fmul_rn(xi, dv), py = __fmul_rn(yi, dv), pz = dv;

    int bn = b * N_ + n;
    const float* K = intr + bn * 9;
    const float* R = rots + bn * 9;
    const float* T = trans + bn * 3;

    float a00 = K[0], a01 = K[1], a02 = K[2];
    float a11 = K[4], a12 = K[5];
    float a22 = K[8];

    float i00 = __fdiv_rn(1.0f, a00);
    float i11 = __fdiv_rn(1.0f, a11);
    float x0  = __fmul_rn(a01, i00);
    float i01 = __fmul_rn(-i11, x0);
    float i22 = __fdiv_rn(1.0f, a22);
    float y0  = __fmul_rn(a02, i00);
    y0 = __fadd_rn(y0, __fmul_rn(a12, i01));
    float y1  = __fmul_rn(a12, i11);
    float i02 = __fmul_rn(-i22, y0);
    float i12 = __fmul_rn(-i22, y1);
    float i10 = 0.f, i20 = 0.f, i21 = 0.f;

    float r00 = R[0], r01 = R[1], r02 = R[2];
    float r10 = R[3], r11 = R[4], r12 = R[5];
    float r20 = R[6], r21 = R[7], r22 = R[8];

#define MM(u0,u1,u2, v0,v1,v2) \
    __fmaf_rn(u2, v2, __fmaf_rn(u1, v1, __fmul_rn(u0, v0)))
    float c00 = MM(r00, r01, r02, i00, i10, i20);
    float c01 = MM(r00, r01, r02, i01, i11, i21);
    float c02 = MM(r00, r01, r02, i02, i12, i22);
    float c10 = MM(r10, r11, r12, i00, i10, i20);
    float c11 = MM(r10, r11, r12, i01, i11, i21);
    float c12 = MM(r10, r11, r12, i02, i12, i22);
    float c20 = MM(r20, r21, r22, i00, i10, i20);
    float c21 = MM(r20, r21, r22, i01, i11, i21);
    float c22 = MM(r20, r21, r22, i02, i12, i22);
#undef MM

#define DOT3(u0,v0,u1,v1,u2,v2) \
    __fadd_rn(__fadd_rn(__fmul_rn(u0,v0), __fmul_rn(u1,v1)), __fmul_rn(u2,v2))
    float gx = __fadd_rn(DOT3(c00,px, c01,py, c02,pz), T[0]);
    float gy = __fadd_rn(DOT3(c10,px, c11,py, c12,pz), T[1]);
    float gz = __fadd_rn(DOT3(c20,px, c21,py, c22,pz), T[2]);
#undef DOT3

    int ix = (int)__fmul_rn(__fadd_rn(gx, 50.0f), 2.0f);
    int iy = (int)__fmul_rn(__fadd_rn(gy, 50.0f), 2.0f);
    int iz = (int)__fdiv_rn(__fadd_rn(gz, 10.0f), 20.0f);
    bool kept = (ix >= 0) && (ix < 200) && (iy >= 0) && (iy < 200) && (iz == 0);

    const int bmin = (gb0 * 256) / PPB;       // block spans b in {bmin, bmin+1}
    int lb = 0, slot = 0;
    unsigned epack = 0;
    if (kept) {
        int vl  = ix * 200 + iy;          // 0..39999
        int g   = vl / CH;                // chunk 0..166
        int rel = vl - g * CH;            // 0..239  (8 bits)
        epack = (unsigned)rel | ((unsigned)n << 8) | ((unsigned)hw << 11)
              | ((unsigned)d << 16);
        lb  = (b - bmin) * NCH + g;       // 0..333
        slot = atomicAdd(&lcnt[lb], 1);   // LDS atomic: fast
    }
    __syncthreads();
    for (int i = t; i < 2 * NCH; i += 256)
        if (lcnt[i] > 0)
            lbase[i] = atomicAdd(&cnt[bmin * NCH + i], lcnt[i]);
    __syncthreads();
    if (kept) {
        entries[(size_t)(bmin * NCH + lb) * ESTR + lbase[lb] + slot] = epack;
    }
}

// ---------------------------------------------------------------------------
// K3: splat, entry-once form. One block per (b, 240-voxel chunk): plane
// [240][64] (stride 65 -> atomics 2-way-free, stores conflict-free). Each
// entry processed ONCE: 64 lanes split channels (feat row is one coalesced
// 256B read from the new [bn][hw][c] layout; entry+depth broadcast). 47K
// entry-visits total vs 3M before. 62.4KB LDS -> 2 blocks/CU keeps the
// store stream overlapped with the next block's zero/scan.
// ---------------------------------------------------------------------------
__global__ __launch_bounds__(256) void k_splat(
    const float* __restrict__ feat, const float* __restrict__ depth,
    const int* __restrict__ cnt, const unsigned* __restrict__ entries,
    float* __restrict__ out)
{
    __shared__ float plane[CH * PLS];     // 62400 B
    const int bid = blockIdx.x;
    const int b   = bid / NCH;
    const int g   = bid - b * NCH;
    const int t   = threadIdx.x;
    float4* pl4 = (float4*)plane;

    for (int i = t; i < (CH * PLS) / 4; i += 256)
        pl4[i] = make_float4(0.f, 0.f, 0.f, 0.f);
    __syncthreads();

    const int bkt = b * NCH + g;
    const int ne = cnt[bkt];
    const unsigned* eb = entries + (size_t)bkt * ESTR;
    const float* db = depth + (size_t)b * PPB;
    const float* fb = feat + (size_t)b * (N_ * HW * C_);
    const int c = t & 63;
    for (int i = (t >> 6); i < ne; i += 4) {
        unsigned e = eb[i];               // broadcast within each wave-quarter
        int rel = e & 255u;
        int n   = (e >> 8) & 7u;
        int hw  = (e >> 11) & 31u;
        int d   = (e >> 16) & 63u;
        float dp = db[n * PBN + d * HW + hw];          // broadcast
        float fv = fb[(n * HW + hw) * C_ + c];         // coalesced 256B row
        atomicAdd(&plane[rel * PLS + c], dp * fv);
    }
    __syncthreads();

    const int base = g * CH;              // first voxel of this chunk
    for (int i = t; i < C_ * CH; i += 256) {
        int cc = i / CH, v = i - cc * CH; // consecutive lanes -> consecutive v
        if (base + v < 40000)
            out[((size_t)(b * C_ + cc)) * 40000 + base + v] = plane[v * PLS + cc];
    }
}

// ---------------------------------------------------------------------------
extern "C" void kernel_launch(void* const* d_in, const int* in_sizes, int n_in,
                              void* d_out, int out_size, void* d_ws, size_t ws_size,
                              hipStream_t stream) {
    const float *x = nullptr, *m1 = nullptr, *m2 = nullptr, *trn = nullptr,
                *w = nullptr, *bias = nullptr;
    for (int i = 0; i < n_in; i++) {
        const float* p = (const float*)d_in[i];
        switch (in_sizes[i]) {
            case 3538944: x = p; break;
            case 1728:    if (!m1) m1 = p; else m2 = p; break;
            case 576:     trn = p; break;
            case 80640:   w = p; break;
            case 105:     bias = p; break;
            default: break;
        }
    }
    if (!x)    x    = (const float*)d_in[0];
    if (!m1)   m1   = (const float*)d_in[1];
    if (!trn)  trn  = (const float*)d_in[2];
    if (!m2)   m2   = (const float*)d_in[3];
    if (!w)    w    = (const float*)d_in[4];
    if (!bias) bias = (const float*)d_in[5];

    float*    feat_ws  = (float*)d_ws;                 // 192*1536 f32 ([bn][hw][c])
    float*    depth_ws = feat_ws + 192 * C_ * HW;      // NPTS f32
    int*      cnt      = (int*)(depth_ws + NPTS);      // NBKT i32
    unsigned* entries  = (unsigned*)(cnt + NBKT);      // NBKT*ESTR u32 (~44 MB)

    float* out    = (float*)d_out;
    float* dlogit = out + FINAL_ELEMS;

    hipMemsetAsync(cnt, 0, NBKT * sizeof(int), stream);
    k_fused<<<CONVB + 738, 256, 0, stream>>>(x, w, bias, m1, trn, m2,
                                             feat_ws, depth_ws, dlogit,
                                             cnt, entries);
    k_splat<<<NBKT, 256, 0, stream>>>(feat_ws, depth_ws, cnt, entries, out);
}

// Round 9
// 448.260 us; speedup vs baseline: 1.0690x; 1.0472x over previous
//
#include <hip/hip_runtime.h>
#include <hip/hip_bf16.h>

#define B_    32
#define N_    6
#define D_    41
#define C_    64
#define FH_   4
#define FW_   6
#define INCH  768
#define HW    24
#define O_    105
#define PBN   984
#define PPB   5904
#define NPTS  188928
#define FINAL_ELEMS 81920000
#define NSEG  8          // planes per b (5000 voxels each)
#define SEGV  5000       // voxels per segment
#define CONVB 192        // conv blocks; 369 geom blocks follow (369*512==NPTS)

// ws: feat f32[192*1536] | depth f32[NPTS] | cnt i32[256] | entries u32[256*PPB]
// entry = { d(6b)<<21 | nhw(8b)<<13 | rel(13b) }

// ---------------------------------------------------------------------------
// K1 fused dispatch, 512-thread blocks.
// blocks [0,192): conv+softmax for one bn. Compute threads t<420: each does
//   3 output rows x 2 hw cols (float2 xs reads). Same LDS read volume as the
//   256-thread form but 2 waves/SIMD -> w-load latency hidden (the measured
//   33.6us vs 7.7us VALU / 12.6us LDS floor was 1-wave/SIMD latency exposure).
//   Channel accumulation order per output unchanged -> bit-identical conv.
// blocks [192,561): geometry+compaction, 512 threads (binning bit-identical).
// ---------------------------------------------------------------------------
__global__ __launch_bounds__(512) void k_fused(
    const float* __restrict__ x, const float* __restrict__ w,
    const float* __restrict__ bias,
    const float* __restrict__ m1, const float* __restrict__ trans,
    const float* __restrict__ m2,
    float* __restrict__ feat_ws, float* __restrict__ depth_ws,
    float* __restrict__ dlogit,
    int* __restrict__ cnt, unsigned* __restrict__ entries)
{
    __shared__ float xs[9216];      // half of x[bn]: 384 c x 24 hw (36 KB)
    __shared__ float ys[O_ * HW];   // full y image (10 KB)
    __shared__ float smax[HW], srs[HW];
    __shared__ int lcnt[16], lbase[16];

    const int t = threadIdx.x;

    if (blockIdx.x < CONVB) {
        // =================== CONV PATH ===================
        const int bn  = blockIdx.x;
        const int og  = t / 12;         // 35 groups x 3 rows = 105 (t<420)
        const int q12 = t % 12;         // hw pair: cols q12*2, q12*2+1

        float a[3][2] = {{0.f,0.f},{0.f,0.f},{0.f,0.f}};
        const int o0 = og * 3;
        const float4* wr0 = (const float4*)(w + (size_t)(o0 + 0) * INCH);
        const float4* wr1 = (const float4*)(w + (size_t)(o0 + 1) * INCH);
        const float4* wr2 = (const float4*)(w + (size_t)(o0 + 2) * INCH);
        float4* xs4 = (float4*)xs;
        const float2* xs2 = (const float2*)xs;

        for (int half = 0; half < 2; ++half) {
            if (half) __syncthreads();                 // drain half-0 readers
            const float4* xg = (const float4*)(x + (size_t)bn * (INCH * HW)) + half * 2304;
            for (int i = t; i < 2304; i += 512) xs4[i] = xg[i];
            __syncthreads();

            if (t < 420) {
                const int wb = half * 96;              // float4 index into w row
                for (int c4 = 0; c4 < 96; ++c4) {
                    float4 w0 = wr0[wb + c4];
                    float4 w1 = wr1[wb + c4];
                    float4 w2 = wr2[wb + c4];
                    int cb = c4 * 4;
                    float2 x0 = xs2[(cb + 0) * 12 + q12];
                    float2 x1 = xs2[(cb + 1) * 12 + q12];
                    float2 x2 = xs2[(cb + 2) * 12 + q12];
                    float2 x3 = xs2[(cb + 3) * 12 + q12];
                    a[0][0]=fmaf(w0.x,x0.x,a[0][0]); a[0][1]=fmaf(w0.x,x0.y,a[0][1]);
                    a[1][0]=fmaf(w1.x,x0.x,a[1][0]); a[1][1]=fmaf(w1.x,x0.y,a[1][1]);
                    a[2][0]=fmaf(w2.x,x0.x,a[2][0]); a[2][1]=fmaf(w2.x,x0.y,a[2][1]);
                    a[0][0]=fmaf(w0.y,x1.x,a[0][0]); a[0][1]=fmaf(w0.y,x1.y,a[0][1]);
                    a[1][0]=fmaf(w1.y,x1.x,a[1][0]); a[1][1]=fmaf(w1.y,x1.y,a[1][1]);
                    a[2][0]=fmaf(w2.y,x1.x,a[2][0]); a[2][1]=fmaf(w2.y,x1.y,a[2][1]);
                    a[0][0]=fmaf(w0.z,x2.x,a[0][0]); a[0][1]=fmaf(w0.z,x2.y,a[0][1]);
                    a[1][0]=fmaf(w1.z,x2.x,a[1][0]); a[1][1]=fmaf(w1.z,x2.y,a[1][1]);
                    a[2][0]=fmaf(w2.z,x2.x,a[2][0]); a[2][1]=fmaf(w2.z,x2.y,a[2][1]);
                    a[0][0]=fmaf(w0.w,x3.x,a[0][0]); a[0][1]=fmaf(w0.w,x3.y,a[0][1]);
                    a[1][0]=fmaf(w1.w,x3.x,a[1][0]); a[1][1]=fmaf(w1.w,x3.y,a[1][1]);
                    a[2][0]=fmaf(w2.w,x3.x,a[2][0]); a[2][1]=fmaf(w2.w,x3.y,a[2][1]);
                }
            }
        }

        if (t < 420) {
#pragma unroll
            for (int r = 0; r < 3; r++) {
                float bo = bias[o0 + r];
#pragma unroll
                for (int j = 0; j < 2; j++)
                    ys[(o0 + r) * HW + q12 * 2 + j] = a[r][j] + bo;
            }
        }
        __syncthreads();

        if (t < HW) {
            float mx = -1e30f;
            for (int d = 0; d < D_; d++) mx = fmaxf(mx, ys[d * HW + t]);
            float s = 0.f;
            for (int d = 0; d < D_; d++) s = __fadd_rn(s, expf(__fsub_rn(ys[d * HW + t], mx)));
            smax[t] = mx; srs[t] = s;
        }
        __syncthreads();

        for (int u = t; u < D_ * HW; u += 512) {
            float yv = ys[u];
            int hw = u % HW;
            depth_ws[bn * PBN + u] = __fdiv_rn(expf(__fsub_rn(yv, smax[hw])), srs[hw]);
            dlogit[(size_t)bn * PBN + u] = yv;
        }
        for (int u = t; u < C_ * HW; u += 512)
            feat_ws[(size_t)bn * (C_ * HW) + u] = ys[D_ * HW + u];
        return;
    }

    // =================== GEOM PATH ===================
    const float* rots = (fabsf(m1[0]) > 50.0f) ? m2 : m1;
    const float* intr = (fabsf(m1[0]) > 50.0f) ? m1 : m2;

    const int gb0 = blockIdx.x - CONVB;       // 0..368
    int p = gb0 * 512 + t;                    // 369*512 == 188928
    if (t < 16) lcnt[t] = 0;
    __syncthreads();

    int b  = p / PPB;
    int pl = p % PPB;
    int n  = pl / PBN;
    int r  = pl % PBN;
    int d  = r / HW;
    int hw = r % HW;
    int h = hw / FW_, wp = hw % FW_;

    float dv = 4.0f + (float)d;
    float xi = (float)((double)wp * (199.0 / 5.0));
    float yi = (float)((double)h  * (149.0 / 3.0));
    float px = __fmul_rn(xi, dv), py = __fmul_rn(yi, dv), pz = dv;

    int bn = b * N_ + n;
    const float* K = intr + bn * 9;
    const float* R = rots + bn * 9;
    const float* T = trans + bn * 3;

    float a00 = K[0], a01 = K[1], a02 = K[2];
    float a11 = K[4], a12 = K[5];
    float a22 = K[8];

    float i00 = __fdiv_rn(1.0f, a00);
    float i11 = __fdiv_rn(1.0f, a11);
    float x0  = __fmul_rn(a01, i00);
    float i01 = __fmul_rn(-i11, x0);
    float i22 = __fdiv_rn(1.0f, a22);
    float y0  = __fmul_rn(a02, i00);
    y0 = __fadd_rn(y0, __fmul_rn(a12, i01));
    float y1  = __fmul_rn(a12, i11);
    float i02 = __fmul_rn(-i22, y0);
    float i12 = __fmul_rn(-i22, y1);
    float i10 = 0.f, i20 = 0.f, i21 = 0.f;

    float r00 = R[0], r01 = R[1], r02 = R[2];
    float r10 = R[3], r11 = R[4], r12 = R[5];
    float r20 = R[6], r21 = R[7], r22 = R[8];

#define MM(u0,u1,u2, v0,v1,v2) \
    __fmaf_rn(u2, v2, __fmaf_rn(u1, v1, __fmul_rn(u0, v0)))
    float c00 = MM(r00, r01, r02, i00, i10, i20);
    float c01 = MM(r00, r01, r02, i01, i11, i21);
    float c02 = MM(r00, r01, r02, i02, i12, i22);
    float c10 = MM(r10, r11, r12, i00, i10, i20);
    float c11 = MM(r10, r11, r12, i01, i11, i21);
    float c12 = MM(r10, r11, r12, i02, i12, i22);
    float c20 = MM(r20, r21, r22, i00, i10, i20);
    float c21 = MM(r20, r21, r22, i01, i11, i21);
    float c22 = MM(r20, r21, r22, i02, i12, i22);
#undef MM

#define DOT3(u0,v0,u1,v1,u2,v2) \
    __fadd_rn(__fadd_rn(__fmul_rn(u0,v0), __fmul_rn(u1,v1)), __fmul_rn(u2,v2))
    float gx = __fadd_rn(DOT3(c00,px, c01,py, c02,pz), T[0]);
    float gy = __fadd_rn(DOT3(c10,px, c11,py, c12,pz), T[1]);
    float gz = __fadd_rn(DOT3(c20,px, c21,py, c22,pz), T[2]);
#undef DOT3

    int ix = (int)__fmul_rn(__fadd_rn(gx, 50.0f), 2.0f);
    int iy = (int)__fmul_rn(__fadd_rn(gy, 50.0f), 2.0f);
    int iz = (int)__fdiv_rn(__fadd_rn(gz, 10.0f), 20.0f);
    bool kept = (ix >= 0) && (ix < 200) && (iy >= 0) && (iy < 200) && (iz == 0);

    const int bmin = (gb0 * 512) / PPB;       // block spans b in {bmin, bmin+1}
    int lb = 0, slot = 0;
    unsigned epack = 0;
    if (kept) {
        int vl  = ix * 200 + iy;          // 0..39999
        int g   = vl / SEGV;              // segment 0..7
        int rel = vl - g * SEGV;          // 0..4999  (13 bits)
        int nhw = n * HW + hw;            // 0..143   (8 bits)
        epack = (unsigned)rel | ((unsigned)nhw << 13) | ((unsigned)d << 21);
        lb  = (b - bmin) * NSEG + g;      // 0..15
        slot = atomicAdd(&lcnt[lb], 1);   // LDS atomic: fast
    }
    __syncthreads();
    if (t < 16 && lcnt[t] > 0) {
        int gbk = (bmin + (t >> 3)) * NSEG + (t & 7);
        lbase[t] = atomicAdd(&cnt[gbk], lcnt[t]);
    }
    __syncthreads();
    if (kept) {
        int gbk = (bmin + (lb >> 3)) * NSEG + (lb & 7);
        entries[(size_t)gbk * PPB + lbase[lb] + slot] = epack;
    }
}

// ---------------------------------------------------------------------------
// K3: splat -> f32 out (R5 form exactly — best measured of 4 structures).
// One block per (b,c,segment); 20KB LDS plane; compacted 4B-entry scan
// (depth re-gathered from L2-resident depth_ws); LDS atomics; float4 stores.
// ---------------------------------------------------------------------------
__global__ __launch_bounds__(256) void k_splat(
    const float* __restrict__ feat, const float* __restrict__ depth,
    const int* __restrict__ cnt, const unsigned* __restrict__ entries,
    float* __restrict__ out)
{
    __shared__ float plane[SEGV];         // 20 KB
    __shared__ float ftab[144];           // feat[b, n, c, hw] for this c
    int bid = blockIdx.x;
    int b   = bid >> 9;                   // /512
    int rem = bid & 511;
    int c   = rem >> 3;
    int g   = rem & 7;
    int t   = threadIdx.x;
    float4* pl4 = (float4*)plane;

    for (int i = t; i < SEGV / 4; i += 256) pl4[i] = make_float4(0.f, 0.f, 0.f, 0.f);
    if (t < 144) {
        int n  = t / HW;
        int hw = t - n * HW;
        ftab[t] = feat[(size_t)(b * N_ + n) * (C_ * HW) + c * HW + hw];
    }
    __syncthreads();

    const int bkt = b * NSEG + g;
    const int ne = cnt[bkt];
    const unsigned* eb = entries + (size_t)bkt * PPB;
    const float* db = depth + (size_t)b * PPB;
    for (int i = t; i < ne; i += 256) {
        unsigned e = eb[i];
        int rel = e & 8191u;
        int nhw = (e >> 13) & 255u;
        int d   = e >> 21;
        int n   = nhw / HW;
        int hw  = nhw - n * HW;
        float dp = db[n * PBN + d * HW + hw];
        atomicAdd(&plane[rel], dp * ftab[nhw]);
    }
    __syncthreads();

    float4* ob = (float4*)(out + ((size_t)(b * C_ + c) * 40000) + g * SEGV);
    for (int i = t; i < SEGV / 4; i += 256) ob[i] = pl4[i];
}

// ---------------------------------------------------------------------------
extern "C" void kernel_launch(void* const* d_in, const int* in_sizes, int n_in,
                              void* d_out, int out_size, void* d_ws, size_t ws_size,
                              hipStream_t stream) {
    const float *x = nullptr, *m1 = nullptr, *m2 = nullptr, *trn = nullptr,
                *w = nullptr, *bias = nullptr;
    for (int i = 0; i < n_in; i++) {
        const float* p = (const float*)d_in[i];
        switch (in_sizes[i]) {
            case 3538944: x = p; break;
            case 1728:    if (!m1) m1 = p; else m2 = p; break;
            case 576:     trn = p; break;
            case 80640:   w = p; break;
            case 105:     bias = p; break;
            default: break;
        }
    }
    if (!x)    x    = (const float*)d_in[0];
    if (!m1)   m1   = (const float*)d_in[1];
    if (!trn)  trn  = (const float*)d_in[2];
    if (!m2)   m2   = (const float*)d_in[3];
    if (!w)    w    = (const float*)d_in[4];
    if (!bias) bias = (const float*)d_in[5];

    float*    feat_ws  = (float*)d_ws;                 // 192*1536 f32
    float*    depth_ws = feat_ws + 192 * C_ * HW;      // NPTS f32
    int*      cnt      = (int*)(depth_ws + NPTS);      // 256 i32
    unsigned* entries  = (unsigned*)(cnt + 256);       // 256*PPB u32 (~6 MB)

    float* out    = (float*)d_out;
    float* dlogit = out + FINAL_ELEMS;

    hipMemsetAsync(cnt, 0, 256 * sizeof(int), stream);
    k_fused<<<CONVB + 369, 512, 0, stream>>>(x, w, bias, m1, trn, m2,
                                             feat_ws, depth_ws, dlogit,
                                             cnt, entries);
    k_splat<<<16384, 256, 0, stream>>>(feat_ws, depth_ws, cnt, entries, out);
}